// Round 8
// baseline (279.440 us; speedup 1.0000x reference)
//
#include <hip/hip_runtime.h>

#define DIM 64
#define NCLS 249
#define SCAN_CHUNK 1024
#define NCHUNK 192
#define PSHIFT 7
#define PSIZE 128
#define SBITS 17
#define SMASK ((1u << SBITS) - 1)
#define MAXP 1024   // max partitions (N <= 131072)

typedef unsigned int u32;
typedef unsigned short u16;
using bf16x8 = __attribute__((ext_vector_type(8))) short;
using f32x4  = __attribute__((ext_vector_type(4))) float;

__device__ __forceinline__ u16 f2bf(float f) {
    u32 u = __builtin_bit_cast(u32, f);
    u += 0x7FFFu + ((u >> 16) & 1u);   // round-to-nearest-even
    return (u16)(u >> 16);
}
__device__ __forceinline__ float bf_lo(u32 u) { return __builtin_bit_cast(float, u << 16); }
__device__ __forceinline__ float bf_hi(u32 u) { return __builtin_bit_cast(float, u & 0xFFFF0000u); }

// ---------------- pass 1: per-(chunk,part) edge counts (part-major out) ----------------
__global__ __launch_bounds__(256) void bucket_count(const int* __restrict__ dst, int E,
                                                    int chunk_size, int nxp,
                                                    int* __restrict__ bcnt) {
    __shared__ int c[MAXP];
    int t = threadIdx.x;
    for (int i = t; i < nxp; i += 256) c[i] = 0;
    __syncthreads();
    int base = blockIdx.x * chunk_size;
    int end = min(base + chunk_size, E);
    for (int e = base + t; e < end; e += 256) {
        int d = __builtin_nontemporal_load(&dst[e]);
        atomicAdd(&c[d >> PSHIFT], 1);
    }
    __syncthreads();
    for (int i = t; i < nxp; i += 256) bcnt[i * NCHUNK + blockIdx.x] = c[i];
}

// ---------------- 3-level exclusive scan of bcnt -> boff (+ sentinel) ----------------
__global__ __launch_bounds__(256) void scan_block_sums(const int* __restrict__ cnt, int n,
                                                       int* __restrict__ bsum) {
    __shared__ int sdata[256];
    int b = blockIdx.x, t = threadIdx.x;
    int base = b * SCAN_CHUNK;
    int s = 0;
    for (int i = t; i < SCAN_CHUNK; i += 256) {
        int idx = base + i;
        s += (idx < n) ? cnt[idx] : 0;
    }
    sdata[t] = s;
    __syncthreads();
    for (int off = 128; off > 0; off >>= 1) {
        if (t < off) sdata[t] += sdata[t + off];
        __syncthreads();
    }
    if (t == 0) bsum[b] = sdata[0];
}

__global__ __launch_bounds__(1024) void scan_bsum(int* __restrict__ bsum, int nb) {
    __shared__ int tmp[1024];
    int t = threadIdx.x;
    int v = (t < nb) ? bsum[t] : 0;
    tmp[t] = v;
    __syncthreads();
    for (int off = 1; off < 1024; off <<= 1) {
        int u = (t >= off) ? tmp[t - off] : 0;
        __syncthreads();
        tmp[t] += u;
        __syncthreads();
    }
    if (t < nb) bsum[t] = tmp[t] - v;
}

__global__ __launch_bounds__(256) void scan_final_boff(const int* __restrict__ cnt, int n,
                                                       const int* __restrict__ bsum,
                                                       int* __restrict__ boff, int total) {
    __shared__ int tsum[256];
    int b = blockIdx.x, t = threadIdx.x;
    int base = b * SCAN_CHUNK + t * 4;
    int v[4];
    int s = 0;
#pragma unroll
    for (int i = 0; i < 4; ++i) {
        int id = base + i;
        v[i] = (id < n) ? cnt[id] : 0;
        s += v[i];
    }
    tsum[t] = s;
    __syncthreads();
    for (int off = 1; off < 256; off <<= 1) {
        int u = (t >= off) ? tsum[t - off] : 0;
        __syncthreads();
        tsum[t] += u;
        __syncthreads();
    }
    int run = tsum[t] - s + bsum[b];
#pragma unroll
    for (int i = 0; i < 4; ++i) {
        int id = base + i;
        if (id < n) boff[id] = run;
        run += v[i];
    }
    if (b == 0 && t == 0) boff[n] = total;
}

// ---------------- pass 2: scatter packed edges into per-part buckets ----------------
__global__ __launch_bounds__(256) void bucket_scatter(const int* __restrict__ ei, int E,
                                                      int chunk_size, int nxp,
                                                      const int* __restrict__ boff,
                                                      u32* __restrict__ bucket) {
    __shared__ int cur[MAXP];
    int t = threadIdx.x;
    for (int i = t; i < nxp; i += 256) cur[i] = boff[i * NCHUNK + blockIdx.x];
    __syncthreads();
    int base = blockIdx.x * chunk_size;
    int end = min(base + chunk_size, E);
    for (int e = base + t; e < end; e += 256) {
        int s = __builtin_nontemporal_load(&ei[e]);
        int d = __builtin_nontemporal_load(&ei[E + e]);
        int pos = atomicAdd(&cur[d >> PSHIFT], 1);
        bucket[pos] = ((u32)(d & (PSIZE - 1)) << SBITS) | (u32)s;
    }
}

// ---------------- counting-sort each partition slice -> nbr + row_ptr ----------------
__global__ __launch_bounds__(256) void sort_bucket(const u32* __restrict__ bucket,
                                                   const int* __restrict__ boff,
                                                   int* __restrict__ nbr,
                                                   int* __restrict__ row_ptr,
                                                   int n, int E) {
    __shared__ int cnt[PSIZE];
    __shared__ int sc[PSIZE];
    __shared__ int cur[PSIZE];
    int t = threadIdx.x;
    int p = blockIdx.x;
    if (t < PSIZE) cnt[t] = 0;
    __syncthreads();
    int beg = boff[p * NCHUNK];
    int end = boff[(p + 1) * NCHUNK];   // sentinel covers last partition
    for (int i = beg + t; i < end; i += 256)
        atomicAdd(&cnt[bucket[i] >> SBITS], 1);
    __syncthreads();
    if (t < PSIZE) sc[t] = cnt[t];
    __syncthreads();
    for (int off = 1; off < PSIZE; off <<= 1) {
        int v = 0;
        if (t < PSIZE && t >= off) v = sc[t - off];
        __syncthreads();
        if (t < PSIZE) sc[t] += v;
        __syncthreads();
    }
    if (t < PSIZE) {
        int excl = beg + sc[t] - cnt[t];
        cur[t] = excl;
        int node = p * PSIZE + t;
        if (node < n) row_ptr[node] = excl;
    }
    if (p == 0 && t == 0) row_ptr[n] = E;
    __syncthreads();
    for (int i = beg + t; i < end; i += 256) {
        u32 pk = bucket[i];
        int pos = atomicAdd(&cur[pk >> SBITS], 1);
        nbr[pos] = (int)(pk & SMASK);
    }
}

// ---------------- fused prep: convert x -> A1 cols 64..127, build B1, B2 ----------------
__global__ void prep_all(const float* __restrict__ x, u16* __restrict__ A1, int nx8,
                         const float* __restrict__ W1l, const float* __restrict__ W1r,
                         u16* __restrict__ B1,
                         const float* __restrict__ W2l, const float* __restrict__ W2r,
                         u16* __restrict__ B2) {
    int i = blockIdx.x * 256 + threadIdx.x;
    if (i < nx8) {
        int node = i >> 3, seg = i & 7;
        const float4 v0 = *(const float4*)(x + (size_t)i * 8);
        const float4 v1 = *(const float4*)(x + (size_t)i * 8 + 4);
        uint4 o;
        o.x = (u32)f2bf(v0.x) | ((u32)f2bf(v0.y) << 16);
        o.y = (u32)f2bf(v0.z) | ((u32)f2bf(v0.w) << 16);
        o.z = (u32)f2bf(v1.x) | ((u32)f2bf(v1.y) << 16);
        o.w = (u32)f2bf(v1.z) | ((u32)f2bf(v1.w) << 16);
        *(uint4*)(A1 + (size_t)node * 128 + 64 + seg * 8) = o;
        return;
    }
    int j = i - nx8;
    if (j < 64 * 128) {
        int r = j >> 7, k = j & 127;
        B1[j] = f2bf(k < 64 ? W1l[r * 64 + k] : W1r[r * 64 + k - 64]);
        return;
    }
    j -= 64 * 128;
    if (j < 256 * 128) {
        int r = j >> 7, k = j & 127;
        float v = 0.f;
        if (r < NCLS) v = (k < 64) ? W2l[r * 64 + k] : W2r[r * 64 + k - 64];
        B2[j] = f2bf(v);
    }
}

// ---------------- pull aggregation: shuffle-shared nbr, 8-edge batches ----------------
__global__ __launch_bounds__(256) void pull_bf16(const u16* __restrict__ Asrc,
                                                 const int* __restrict__ row_ptr,
                                                 const int* __restrict__ nbr,
                                                 u16* __restrict__ Adst, int n) {
    int tid = blockIdx.x * 256 + threadIdx.x;
    int node = tid >> 3;
    int q = tid & 7;
    if (node >= n) return;
    int beg = row_ptr[node], end = row_ptr[node + 1];
    float a0 = 0.f, a1 = 0.f, a2 = 0.f, a3 = 0.f, a4 = 0.f, a5 = 0.f, a6 = 0.f, a7 = 0.f;
    for (int j0 = beg; j0 < end; j0 += 8) {
        int myj = j0 + q;
        int smine = (myj < end) ? nbr[myj] : 0;   // coalesced: 8 lanes, 8 entries
        int cnt = min(8, end - j0);
#pragma unroll 4
        for (int k = 0; k < cnt; ++k) {
            int s = __shfl(smine, k, 8);          // distribute index to group
            uint4 v = *(const uint4*)(Asrc + (size_t)s * 128 + 64 + q * 8);
            a0 += bf_lo(v.x); a1 += bf_hi(v.x);
            a2 += bf_lo(v.y); a3 += bf_hi(v.y);
            a4 += bf_lo(v.z); a5 += bf_hi(v.z);
            a6 += bf_lo(v.w); a7 += bf_hi(v.w);
        }
    }
    uint4 o;
    o.x = (u32)f2bf(a0) | ((u32)f2bf(a1) << 16);
    o.y = (u32)f2bf(a2) | ((u32)f2bf(a3) << 16);
    o.z = (u32)f2bf(a4) | ((u32)f2bf(a5) << 16);
    o.w = (u32)f2bf(a6) | ((u32)f2bf(a7) << 16);
    *(uint4*)(Adst + (size_t)node * 128 + q * 8) = o;
}

// ---------------- MFMA GEMM: [64 nodes] x [NT*16 cols], K=128 ----------------
template<int NT, bool RELU, bool OUT_BF16>
__global__ __launch_bounds__(256) void gemm_kernel(
    const u16* __restrict__ A, const u16* __restrict__ B,
    const float* __restrict__ bias,
    float* __restrict__ outf, u16* __restrict__ outb,
    int n_nodes, int n_cols)
{
    constexpr int KC = (NT == 16) ? 2 : 1;
    constexpr int KW = 128 / KC;
    constexpr int RG = KW / 8;
    constexpr int NR = NT * 16;
    __shared__ uint4 A_lds[64 * 16];
    __shared__ uint4 B_lds[2048];

    const int t = threadIdx.x;
    const int node0 = blockIdx.x * 64;

#pragma unroll
    for (int i = 0; i < 4; ++i) {
        int gl = t + 256 * i;
        int r = gl >> 4, g = gl & 15;
        uint4 v = make_uint4(0u, 0u, 0u, 0u);
        int node = node0 + r;
        if (node < n_nodes) v = *(const uint4*)(A + (size_t)node * 128 + g * 8);
        A_lds[r * 16 + (g ^ (r & 7))] = v;
    }

    const int w  = t >> 6;
    const int l  = t & 63;
    const int lm = l & 15;
    const int lg = l >> 4;
    const int arow = w * 16 + lm;
    const int asw  = arow & 7;

    f32x4 acc[NT];
#pragma unroll
    for (int n = 0; n < NT; ++n) acc[n] = f32x4{0.f, 0.f, 0.f, 0.f};

#pragma unroll
    for (int kc = 0; kc < KC; ++kc) {
        __syncthreads();
#pragma unroll
        for (int i = 0; i < (NR * RG) / 256; ++i) {
            int gl = t + 256 * i;
            int r = gl / RG, g = gl % RG;
            uint4 v = *(const uint4*)(B + (size_t)r * 128 + kc * KW + g * 8);
            B_lds[r * RG + (g ^ (r & 7))] = v;
        }
        __syncthreads();
#pragma unroll
        for (int ks = 0; ks < KW / 32; ++ks) {
            int ag = lg + (kc * (KW / 32) + ks) * 4;
            bf16x8 af = __builtin_bit_cast(bf16x8, A_lds[arow * 16 + (ag ^ asw)]);
#pragma unroll
            for (int n = 0; n < NT; ++n) {
                int brow = n * 16 + lm;
                int bg = lg + ks * 4;
                bf16x8 bf = __builtin_bit_cast(bf16x8, B_lds[brow * RG + (bg ^ (brow & 7))]);
                acc[n] = __builtin_amdgcn_mfma_f32_16x16x32_bf16(af, bf, acc[n], 0, 0, 0);
            }
        }
    }

    const int rbase = w * 16 + lg * 4;
#pragma unroll
    for (int n = 0; n < NT; ++n) {
        int c = n * 16 + lm;
        float bv = (c < n_cols) ? bias[c] : 0.f;
#pragma unroll
        for (int r = 0; r < 4; ++r) {
            int node = node0 + rbase + r;
            if (node < n_nodes && c < n_cols) {
                float v = acc[n][r] + bv;
                if (RELU) v = fmaxf(v, 0.f);
                if (OUT_BF16) outb[(size_t)node * 128 + 64 + c] = f2bf(v);
                else __builtin_nontemporal_store(v, &outf[(size_t)node * (size_t)n_cols + c]);
            }
        }
    }
}

extern "C" void kernel_launch(void* const* d_in, const int* in_sizes, int n_in,
                              void* d_out, int out_size, void* d_ws, size_t ws_size,
                              hipStream_t stream) {
    const float* x   = (const float*)d_in[0];
    const int*   ei  = (const int*)d_in[1];
    const float* W1l = (const float*)d_in[2];
    const float* b1  = (const float*)d_in[3];
    const float* W1r = (const float*)d_in[4];
    const float* W2l = (const float*)d_in[5];
    const float* b2  = (const float*)d_in[6];
    const float* W2r = (const float*)d_in[7];
    float* out = (float*)d_out;

    const int N = in_sizes[0] / DIM;     // 100000  (< 2^17, required by packing)
    const int E = in_sizes[1] / 2;       // 1600000
    const int NPAD = ((N + 63) / 64) * 64;
    const int NXP = (N + PSIZE - 1) / PSIZE;          // 782 partitions
    const int NSC = NXP * NCHUNK;                     // 150144 scan entries
    const int NB2 = (NSC + SCAN_CHUNK - 1) / SCAN_CHUNK;

    // workspace layout
    char* wp = (char*)d_ws;
    u16* A1 = (u16*)wp;                 wp += (size_t)NPAD * 128 * 2;
    u16* A2 = (u16*)wp;                 wp += (size_t)NPAD * 128 * 2;
    u16* B1 = (u16*)wp;                 wp += 64 * 128 * 2;
    u16* B2 = (u16*)wp;                 wp += 256 * 128 * 2;
    int* bcnt = (int*)wp;               wp += (size_t)NSC * 4;
    int* boff = (int*)wp;               wp += (size_t)(NSC + 1) * 4;
    int* bsum = (int*)wp;               wp += 1024 * 4;
    int* row_ptr = (int*)wp;            wp += (size_t)(N + 1) * 4;
    u32* bucket = (u32*)wp;             wp += (size_t)E * 4;
    int* nbr = (int*)wp;                wp += (size_t)E * 4;

    const int chunk_size = (E + NCHUNK - 1) / NCHUNK;

    // ---- bucket build + per-partition counting sort ----
    bucket_count<<<NCHUNK, 256, 0, stream>>>(ei + E, E, chunk_size, NXP, bcnt);
    scan_block_sums<<<NB2, 256, 0, stream>>>(bcnt, NSC, bsum);
    scan_bsum<<<1, 1024, 0, stream>>>(bsum, NB2);
    scan_final_boff<<<NB2, 256, 0, stream>>>(bcnt, NSC, bsum, boff, E);
    bucket_scatter<<<NCHUNK, 256, 0, stream>>>(ei, E, chunk_size, NXP, boff, bucket);
    sort_bucket<<<NXP, 256, 0, stream>>>(bucket, boff, nbr, row_ptr, N, E);

    // ---- fused conversions / weight prep ----
    const int prep_items = N * 8 + 64 * 128 + 256 * 128;
    prep_all<<<(prep_items + 255) / 256, 256, 0, stream>>>(x, A1, N * 8,
                                                           W1l, W1r, B1, W2l, W2r, B2);

    const int gemm_blocks = NPAD / 64;

    // ---- layer 1 ----
    pull_bf16<<<(N * 8 + 255) / 256, 256, 0, stream>>>(A1, row_ptr, nbr, A1, N);
    gemm_kernel<4, true, true><<<gemm_blocks, 256, 0, stream>>>(A1, B1, b1, nullptr, A2, N, 64);

    // ---- layer 2 ----
    pull_bf16<<<(N * 8 + 255) / 256, 256, 0, stream>>>(A2, row_ptr, nbr, A2, N);
    gemm_kernel<16, false, false><<<gemm_blocks, 256, 0, stream>>>(A2, B2, b2, out, nullptr, N, NCLS);
}

// Round 9
// 203.361 us; speedup vs baseline: 1.3741x; 1.3741x over previous
//
#include <hip/hip_runtime.h>

#define DIM 64
#define NCLS 249
#define SCAN_CHUNK 1024
#define NCHUNK 192
#define PSHIFT 7
#define PSIZE 128
#define SBITS 17
#define SMASK ((1u << SBITS) - 1)
#define MAXP 1024   // max partitions (N <= 131072)

typedef unsigned int u32;
typedef unsigned short u16;
using bf16x8 = __attribute__((ext_vector_type(8))) short;
using f32x4  = __attribute__((ext_vector_type(4))) float;

__device__ __forceinline__ u16 f2bf(float f) {
    u32 u = __builtin_bit_cast(u32, f);
    u += 0x7FFFu + ((u >> 16) & 1u);   // round-to-nearest-even
    return (u16)(u >> 16);
}
__device__ __forceinline__ float bf_lo(u32 u) { return __builtin_bit_cast(float, u << 16); }
__device__ __forceinline__ float bf_hi(u32 u) { return __builtin_bit_cast(float, u & 0xFFFF0000u); }

// ---------------- pass 1: per-(chunk,part) edge counts (part-major out) ----------------
__global__ __launch_bounds__(256) void bucket_count(const int* __restrict__ dst, int E,
                                                    int chunk_size, int nxp,
                                                    int* __restrict__ bcnt) {
    __shared__ int c[MAXP];
    int t = threadIdx.x;
    for (int i = t; i < nxp; i += 256) c[i] = 0;
    __syncthreads();
    int base = blockIdx.x * chunk_size;
    int end = min(base + chunk_size, E);
    for (int e = base + t; e < end; e += 256) {
        int d = __builtin_nontemporal_load(&dst[e]);
        atomicAdd(&c[d >> PSHIFT], 1);
    }
    __syncthreads();
    for (int i = t; i < nxp; i += 256) bcnt[i * NCHUNK + blockIdx.x] = c[i];
}

// ---------------- 3-level exclusive scan of bcnt -> boff (+ sentinel) ----------------
__global__ __launch_bounds__(256) void scan_block_sums(const int* __restrict__ cnt, int n,
                                                       int* __restrict__ bsum) {
    __shared__ int sdata[256];
    int b = blockIdx.x, t = threadIdx.x;
    int base = b * SCAN_CHUNK;
    int s = 0;
    for (int i = t; i < SCAN_CHUNK; i += 256) {
        int idx = base + i;
        s += (idx < n) ? cnt[idx] : 0;
    }
    sdata[t] = s;
    __syncthreads();
    for (int off = 128; off > 0; off >>= 1) {
        if (t < off) sdata[t] += sdata[t + off];
        __syncthreads();
    }
    if (t == 0) bsum[b] = sdata[0];
}

__global__ __launch_bounds__(1024) void scan_bsum(int* __restrict__ bsum, int nb) {
    __shared__ int tmp[1024];
    int t = threadIdx.x;
    int v = (t < nb) ? bsum[t] : 0;
    tmp[t] = v;
    __syncthreads();
    for (int off = 1; off < 1024; off <<= 1) {
        int u = (t >= off) ? tmp[t - off] : 0;
        __syncthreads();
        tmp[t] += u;
        __syncthreads();
    }
    if (t < nb) bsum[t] = tmp[t] - v;
}

__global__ __launch_bounds__(256) void scan_final_boff(const int* __restrict__ cnt, int n,
                                                       const int* __restrict__ bsum,
                                                       int* __restrict__ boff, int total) {
    __shared__ int tsum[256];
    int b = blockIdx.x, t = threadIdx.x;
    int base = b * SCAN_CHUNK + t * 4;
    int v[4];
    int s = 0;
#pragma unroll
    for (int i = 0; i < 4; ++i) {
        int id = base + i;
        v[i] = (id < n) ? cnt[id] : 0;
        s += v[i];
    }
    tsum[t] = s;
    __syncthreads();
    for (int off = 1; off < 256; off <<= 1) {
        int u = (t >= off) ? tsum[t - off] : 0;
        __syncthreads();
        tsum[t] += u;
        __syncthreads();
    }
    int run = tsum[t] - s + bsum[b];
#pragma unroll
    for (int i = 0; i < 4; ++i) {
        int id = base + i;
        if (id < n) boff[id] = run;
        run += v[i];
    }
    if (b == 0 && t == 0) boff[n] = total;
}

// ---------------- pass 2: scatter packed edges into per-part buckets ----------------
__global__ __launch_bounds__(256) void bucket_scatter(const int* __restrict__ ei, int E,
                                                      int chunk_size, int nxp,
                                                      const int* __restrict__ boff,
                                                      u32* __restrict__ bucket) {
    __shared__ int cur[MAXP];
    int t = threadIdx.x;
    for (int i = t; i < nxp; i += 256) cur[i] = boff[i * NCHUNK + blockIdx.x];
    __syncthreads();
    int base = blockIdx.x * chunk_size;
    int end = min(base + chunk_size, E);
    for (int e = base + t; e < end; e += 256) {
        int s = __builtin_nontemporal_load(&ei[e]);
        int d = __builtin_nontemporal_load(&ei[E + e]);
        int pos = atomicAdd(&cur[d >> PSHIFT], 1);
        bucket[pos] = ((u32)(d & (PSIZE - 1)) << SBITS) | (u32)s;
    }
}

// ---------------- counting-sort each partition slice -> nbr + row_ptr ----------------
__global__ __launch_bounds__(256) void sort_bucket(const u32* __restrict__ bucket,
                                                   const int* __restrict__ boff,
                                                   int* __restrict__ nbr,
                                                   int* __restrict__ row_ptr,
                                                   int n, int E) {
    __shared__ int cnt[PSIZE];
    __shared__ int sc[PSIZE];
    __shared__ int cur[PSIZE];
    int t = threadIdx.x;
    int p = blockIdx.x;
    if (t < PSIZE) cnt[t] = 0;
    __syncthreads();
    int beg = boff[p * NCHUNK];
    int end = boff[(p + 1) * NCHUNK];   // sentinel covers last partition
    for (int i = beg + t; i < end; i += 256)
        atomicAdd(&cnt[bucket[i] >> SBITS], 1);
    __syncthreads();
    if (t < PSIZE) sc[t] = cnt[t];
    __syncthreads();
    for (int off = 1; off < PSIZE; off <<= 1) {
        int v = 0;
        if (t < PSIZE && t >= off) v = sc[t - off];
        __syncthreads();
        if (t < PSIZE) sc[t] += v;
        __syncthreads();
    }
    if (t < PSIZE) {
        int excl = beg + sc[t] - cnt[t];
        cur[t] = excl;
        int node = p * PSIZE + t;
        if (node < n) row_ptr[node] = excl;
    }
    if (p == 0 && t == 0) row_ptr[n] = E;
    __syncthreads();
    for (int i = beg + t; i < end; i += 256) {
        u32 pk = bucket[i];
        int pos = atomicAdd(&cur[pk >> SBITS], 1);
        nbr[pos] = (int)(pk & SMASK);
    }
}

// ---------------- fused prep: convert x -> A1 cols 64..127, build B1, B2 ----------------
__global__ void prep_all(const float* __restrict__ x, u16* __restrict__ A1, int nx8,
                         const float* __restrict__ W1l, const float* __restrict__ W1r,
                         u16* __restrict__ B1,
                         const float* __restrict__ W2l, const float* __restrict__ W2r,
                         u16* __restrict__ B2) {
    int i = blockIdx.x * 256 + threadIdx.x;
    if (i < nx8) {
        int node = i >> 3, seg = i & 7;
        const float4 v0 = *(const float4*)(x + (size_t)i * 8);
        const float4 v1 = *(const float4*)(x + (size_t)i * 8 + 4);
        uint4 o;
        o.x = (u32)f2bf(v0.x) | ((u32)f2bf(v0.y) << 16);
        o.y = (u32)f2bf(v0.z) | ((u32)f2bf(v0.w) << 16);
        o.z = (u32)f2bf(v1.x) | ((u32)f2bf(v1.y) << 16);
        o.w = (u32)f2bf(v1.z) | ((u32)f2bf(v1.w) << 16);
        *(uint4*)(A1 + (size_t)node * 128 + 64 + seg * 8) = o;
        return;
    }
    int j = i - nx8;
    if (j < 64 * 128) {
        int r = j >> 7, k = j & 127;
        B1[j] = f2bf(k < 64 ? W1l[r * 64 + k] : W1r[r * 64 + k - 64]);
        return;
    }
    j -= 64 * 128;
    if (j < 256 * 128) {
        int r = j >> 7, k = j & 127;
        float v = 0.f;
        if (r < NCLS) v = (k < 64) ? W2l[r * 64 + k] : W2r[r * 64 + k - 64];
        B2[j] = f2bf(v);
    }
}

// ---------------- pull aggregation: shuffle-shared nbr, 8-edge batches ----------------
__global__ __launch_bounds__(256) void pull_bf16(const u16* __restrict__ Asrc,
                                                 const int* __restrict__ row_ptr,
                                                 const int* __restrict__ nbr,
                                                 u16* __restrict__ Adst, int n) {
    int tid = blockIdx.x * 256 + threadIdx.x;
    int node = tid >> 3;
    int q = tid & 7;
    if (node >= n) return;
    int beg = row_ptr[node], end = row_ptr[node + 1];
    float a0 = 0.f, a1 = 0.f, a2 = 0.f, a3 = 0.f, a4 = 0.f, a5 = 0.f, a6 = 0.f, a7 = 0.f;
    for (int j0 = beg; j0 < end; j0 += 8) {
        int myj = j0 + q;
        int smine = (myj < end) ? nbr[myj] : 0;   // coalesced: 8 lanes, 8 entries
        int cnt = min(8, end - j0);
#pragma unroll 4
        for (int k = 0; k < cnt; ++k) {
            int s = __shfl(smine, k, 8);          // distribute index to group
            uint4 v = *(const uint4*)(Asrc + (size_t)s * 128 + 64 + q * 8);
            a0 += bf_lo(v.x); a1 += bf_hi(v.x);
            a2 += bf_lo(v.y); a3 += bf_hi(v.y);
            a4 += bf_lo(v.z); a5 += bf_hi(v.z);
            a6 += bf_lo(v.w); a7 += bf_hi(v.w);
        }
    }
    uint4 o;
    o.x = (u32)f2bf(a0) | ((u32)f2bf(a1) << 16);
    o.y = (u32)f2bf(a2) | ((u32)f2bf(a3) << 16);
    o.z = (u32)f2bf(a4) | ((u32)f2bf(a5) << 16);
    o.w = (u32)f2bf(a6) | ((u32)f2bf(a7) << 16);
    *(uint4*)(Adst + (size_t)node * 128 + q * 8) = o;
}

// ---------------- MFMA GEMM: [64 nodes] x [NT*16 cols], K=128 ----------------
// f32 output path: LDS-transpose epilogue -> coalesced row-major stores
template<int NT, bool RELU, bool OUT_BF16>
__global__ __launch_bounds__(256) void gemm_kernel(
    const u16* __restrict__ A, const u16* __restrict__ B,
    const float* __restrict__ bias,
    float* __restrict__ outf, u16* __restrict__ outb,
    int n_nodes, int n_cols)
{
    constexpr int KC = (NT == 16) ? 2 : 1;
    constexpr int KW = 128 / KC;
    constexpr int RG = KW / 8;
    constexpr int NR = NT * 16;
    __shared__ uint4 smem[3072];          // 48 KB: A_lds[0..1024) | B_lds[1024..3072)
    uint4* A_lds = smem;
    uint4* B_lds = smem + 1024;

    const int t = threadIdx.x;
    const int node0 = blockIdx.x * 64;

#pragma unroll
    for (int i = 0; i < 4; ++i) {
        int gl = t + 256 * i;
        int r = gl >> 4, g = gl & 15;
        uint4 v = make_uint4(0u, 0u, 0u, 0u);
        int node = node0 + r;
        if (node < n_nodes) v = *(const uint4*)(A + (size_t)node * 128 + g * 8);
        A_lds[r * 16 + (g ^ (r & 7))] = v;
    }

    const int w  = t >> 6;
    const int l  = t & 63;
    const int lm = l & 15;
    const int lg = l >> 4;
    const int arow = w * 16 + lm;
    const int asw  = arow & 7;

    f32x4 acc[NT];
#pragma unroll
    for (int n = 0; n < NT; ++n) acc[n] = f32x4{0.f, 0.f, 0.f, 0.f};

#pragma unroll
    for (int kc = 0; kc < KC; ++kc) {
        __syncthreads();
#pragma unroll
        for (int i = 0; i < (NR * RG) / 256; ++i) {
            int gl = t + 256 * i;
            int r = gl / RG, g = gl % RG;
            uint4 v = *(const uint4*)(B + (size_t)r * 128 + kc * KW + g * 8);
            B_lds[r * RG + (g ^ (r & 7))] = v;
        }
        __syncthreads();
#pragma unroll
        for (int ks = 0; ks < KW / 32; ++ks) {
            int ag = lg + (kc * (KW / 32) + ks) * 4;
            bf16x8 af = __builtin_bit_cast(bf16x8, A_lds[arow * 16 + (ag ^ asw)]);
#pragma unroll
            for (int n = 0; n < NT; ++n) {
                int brow = n * 16 + lm;
                int bg = lg + ks * 4;
                bf16x8 bf = __builtin_bit_cast(bf16x8, B_lds[brow * RG + (bg ^ (brow & 7))]);
                acc[n] = __builtin_amdgcn_mfma_f32_16x16x32_bf16(af, bf, acc[n], 0, 0, 0);
            }
        }
    }

    if (OUT_BF16) {
        // bf16 path (layer 1): D col = lane&15 (+tile*16), row = (lane>>4)*4+reg (+wave*16)
        const int rbase = w * 16 + lg * 4;
#pragma unroll
        for (int n = 0; n < NT; ++n) {
            int c = n * 16 + lm;
            float bv = (c < n_cols) ? bias[c] : 0.f;
#pragma unroll
            for (int r = 0; r < 4; ++r) {
                int node = node0 + rbase + r;
                if (node < n_nodes && c < n_cols) {
                    float v = acc[n][r] + bv;
                    if (RELU) v = fmaxf(v, 0.f);
                    outb[(size_t)node * 128 + 64 + c] = f2bf(v);
                }
            }
        }
    } else {
        // f32 path (layer 2): per-wave LDS transpose, coalesced row stores.
        // S[w][8][264] f32 = 33.8 KB, aliases A_lds/B_lds after barrier.
        float bc[NT];
#pragma unroll
        for (int n = 0; n < NT; ++n) {
            int c = n * 16 + lm;
            bc[n] = (c < n_cols) ? bias[c] : 0.f;
        }
        float* S = reinterpret_cast<float*>(smem);
        __syncthreads();   // all waves done reading A_lds/B_lds
#pragma unroll
        for (int rc = 0; rc < 2; ++rc) {
            if (rc) __syncthreads();           // WAR: previous chunk's reads done
            if ((lg >> 1) == rc) {             // lg 0,1 -> rows 0..7; lg 2,3 -> rows 8..15
                int lrow = (lg & 1) * 4;
                float* Sw = S + ((size_t)w * 8 + lrow) * 264;
#pragma unroll
                for (int n = 0; n < NT; ++n) {
#pragma unroll
                    for (int r = 0; r < 4; ++r) {
                        float v = acc[n][r] + bc[n];
                        if (RELU) v = fmaxf(v, 0.f);
                        Sw[r * 264 + n * 16 + lm] = v;
                    }
                }
            }
            __syncthreads();                   // staged rows visible
            const float* Sw = S + (size_t)w * 8 * 264;
#pragma unroll
            for (int row8 = 0; row8 < 8; ++row8) {
                int node = node0 + w * 16 + rc * 8 + row8;   // wave-uniform
                if (node >= n_nodes) continue;
                float* orow = outf + (size_t)node * (size_t)n_cols;
#pragma unroll
                for (int k = 0; k < 4; ++k) {
                    int c = k * 64 + l;        // lanes cover 64 consecutive cols
                    if (c < n_cols) orow[c] = Sw[row8 * 264 + c];
                }
            }
        }
    }
}

extern "C" void kernel_launch(void* const* d_in, const int* in_sizes, int n_in,
                              void* d_out, int out_size, void* d_ws, size_t ws_size,
                              hipStream_t stream) {
    const float* x   = (const float*)d_in[0];
    const int*   ei  = (const int*)d_in[1];
    const float* W1l = (const float*)d_in[2];
    const float* b1  = (const float*)d_in[3];
    const float* W1r = (const float*)d_in[4];
    const float* W2l = (const float*)d_in[5];
    const float* b2  = (const float*)d_in[6];
    const float* W2r = (const float*)d_in[7];
    float* out = (float*)d_out;

    const int N = in_sizes[0] / DIM;     // 100000  (< 2^17, required by packing)
    const int E = in_sizes[1] / 2;       // 1600000
    const int NPAD = ((N + 63) / 64) * 64;
    const int NXP = (N + PSIZE - 1) / PSIZE;          // 782 partitions
    const int NSC = NXP * NCHUNK;                     // 150144 scan entries
    const int NB2 = (NSC + SCAN_CHUNK - 1) / SCAN_CHUNK;

    // workspace layout
    char* wp = (char*)d_ws;
    u16* A1 = (u16*)wp;                 wp += (size_t)NPAD * 128 * 2;
    u16* A2 = (u16*)wp;                 wp += (size_t)NPAD * 128 * 2;
    u16* B1 = (u16*)wp;                 wp += 64 * 128 * 2;
    u16* B2 = (u16*)wp;                 wp += 256 * 128 * 2;
    int* bcnt = (int*)wp;               wp += (size_t)NSC * 4;
    int* boff = (int*)wp;               wp += (size_t)(NSC + 1) * 4;
    int* bsum = (int*)wp;               wp += 1024 * 4;
    int* row_ptr = (int*)wp;            wp += (size_t)(N + 1) * 4;
    u32* bucket = (u32*)wp;             wp += (size_t)E * 4;
    int* nbr = (int*)wp;                wp += (size_t)E * 4;

    const int chunk_size = (E + NCHUNK - 1) / NCHUNK;

    // ---- bucket build + per-partition counting sort ----
    bucket_count<<<NCHUNK, 256, 0, stream>>>(ei + E, E, chunk_size, NXP, bcnt);
    scan_block_sums<<<NB2, 256, 0, stream>>>(bcnt, NSC, bsum);
    scan_bsum<<<1, 1024, 0, stream>>>(bsum, NB2);
    scan_final_boff<<<NB2, 256, 0, stream>>>(bcnt, NSC, bsum, boff, E);
    bucket_scatter<<<NCHUNK, 256, 0, stream>>>(ei, E, chunk_size, NXP, boff, bucket);
    sort_bucket<<<NXP, 256, 0, stream>>>(bucket, boff, nbr, row_ptr, N, E);

    // ---- fused conversions / weight prep ----
    const int prep_items = N * 8 + 64 * 128 + 256 * 128;
    prep_all<<<(prep_items + 255) / 256, 256, 0, stream>>>(x, A1, N * 8,
                                                           W1l, W1r, B1, W2l, W2r, B2);

    const int gemm_blocks = NPAD / 64;

    // ---- layer 1 ----
    pull_bf16<<<(N * 8 + 255) / 256, 256, 0, stream>>>(A1, row_ptr, nbr, A1, N);
    gemm_kernel<4, true, true><<<gemm_blocks, 256, 0, stream>>>(A1, B1, b1, nullptr, A2, N, 64);

    // ---- layer 2 ----
    pull_bf16<<<(N * 8 + 255) / 256, 256, 0, stream>>>(A2, row_ptr, nbr, A2, N);
    gemm_kernel<16, false, false><<<gemm_blocks, 256, 0, stream>>>(A2, B2, b2, out, nullptr, N, NCLS);
}